// Round 14
// baseline (71.662 us; speedup 1.0000x reference)
//
#include <hip/hip_runtime.h>

#define NB 4
#define SEQ 2048
#define EMB 32
#define HEADS 8
#define HD 4

typedef unsigned int uint;

// K and V projections. First half of grid does K, second half V.
__global__ __launch_bounds__(256) void proj_kv_kernel(
    const float* __restrict__ key, const float* __restrict__ value,
    const float* __restrict__ Wk, const float* __restrict__ bk,
    const float* __restrict__ Wv, const float* __restrict__ bv,
    float* __restrict__ Kp, float* __restrict__ Vp) {
  const int half = NB * SEQ / 8;                   // 1024
  bool isV = blockIdx.x >= half;
  const float* X = isV ? value : key;
  const float* W = isV ? Wv : Wk;
  const float* b = isV ? bv : bk;
  float* P = isV ? Vp : Kp;
  int blk = isV ? (blockIdx.x - half) : blockIdx.x;

  __shared__ float sW[EMB][EMB];
  __shared__ float sb[EMB];
  __shared__ float sX[8][EMB];
  int t = threadIdx.x;
  for (int i = t; i < EMB * EMB; i += 256) sW[i >> 5][i & 31] = W[i];
  if (t < EMB) sb[t] = b[t];
  size_t row0 = (size_t)blk * 8;
  int r = t >> 5, c = t & 31;
  sX[r][c] = X[(row0 + r) * EMB + c];
  __syncthreads();
  float acc = sb[c];
#pragma unroll
  for (int d = 0; d < EMB; ++d) acc = fmaf(sX[r][d], sW[d][c], acc);
  P[(row0 + r) * EMB + c] = acc;
}

// 32-key tile: lane (h, ks) -> 64 DISTINCT float4 per load (full 1 KB/instr).
__device__ __forceinline__ void load_tile(
    const float*& kptr, const float*& vptr,
    float4 (&KK)[4], float4 (&VV)[4]) {
  KK[0] = *(const float4*)(kptr);
  KK[1] = *(const float4*)(kptr + EMB);
  KK[2] = *(const float4*)(kptr + 2 * EMB);
  KK[3] = *(const float4*)(kptr + 3 * EMB);
  VV[0] = *(const float4*)(vptr);
  VV[1] = *(const float4*)(vptr + EMB);
  VV[2] = *(const float4*)(vptr + 2 * EMB);
  VV[3] = *(const float4*)(vptr + 3 * EMB);
  kptr += 32 * EMB; vptr += 32 * EMB;
}

// Scalar hot-loop tile: no-max softmax p = exp2(s), maskless.
// SCALAR math on purpose: CDNA4 has no fp32 dual-issue (157 TF = scalar
// v_fma rate); v2f "packing" only added splat-movs (r4-r13 detour).
__device__ __forceinline__ void compute_tile(
    const float4 (&KK)[4], const float4 (&VV)[4],
    const float (&q)[8][4], float (&l)[8], float (&ac)[8][4]) {
#pragma unroll
  for (int j = 0; j < 4; ++j) {
    const float4 kk = KK[j];
    const float4 vv = VV[j];
#pragma unroll
    for (int r = 0; r < 8; ++r) {
      float s = fmaf(q[r][0], kk.x, fmaf(q[r][1], kk.y,
                fmaf(q[r][2], kk.z, q[r][3] * kk.w)));
      float p = __builtin_amdgcn_exp2f(s);
      l[r] += p;
      ac[r][0] = fmaf(p, vv.x, ac[r][0]);
      ac[r][1] = fmaf(p, vv.y, ac[r][1]);
      ac[r][2] = fmaf(p, vv.z, ac[r][2]);
      ac[r][3] = fmaf(p, vv.w, ac[r][3]);
    }
  }
}

// Masked cold-path tile (raw int32 mask; not taken for all-ones bench mask).
__device__ __forceinline__ void compute_tile_masked(
    const float4 (&KK)[4], const float4 (&VV)[4], const int4 (&MQ)[8],
    const float (&q)[8][4], float (&l)[8], float (&ac)[8][4]) {
#pragma unroll
  for (int j = 0; j < 4; ++j) {
    const float4 kk = KK[j];
    const float4 vv = VV[j];
#pragma unroll
    for (int r = 0; r < 8; ++r) {
      float s = fmaf(q[r][0], kk.x, fmaf(q[r][1], kk.y,
                fmaf(q[r][2], kk.z, q[r][3] * kk.w)));
      int m = (j == 0) ? MQ[r].x : (j == 1) ? MQ[r].y : (j == 2) ? MQ[r].z : MQ[r].w;
      float p = m ? __builtin_amdgcn_exp2f(s) : 0.0f;
      l[r] += p;
      ac[r][0] = fmaf(p, vv.x, ac[r][0]);
      ac[r][1] = fmaf(p, vv.y, ac[r][1]);
      ac[r][2] = fmaf(p, vv.z, ac[r][2]);
      ac[r][3] = fmaf(p, vv.w, ac[r][3]);
    }
  }
}

// Fused q-projection + mask check + flash attention (no-max) + out projection.
// Block = 256 threads = 4 waves = 2 row-octets x 2 key-halves; 16 rows/block.
// Wave: R=8 rows/thread, 1024 keys (32 tiles of 32), register double-buffer.
// Lane: h = lane&7, ks = lane>>3 (distinct addresses).
// Mask is read RAW by each wave (32 KB slice, 32 coalesced int4/lane),
// AND-reduced -> maskless hot loop; the 67 MB mask stream overlaps compute
// instead of a serial pack prepass. Grid = NB*SEQ/16 = 512.
// Plain __launch_bounds__(256): VGPR must float to ~160 so the double
// buffer truly lives in registers (a 128 cap forces load-sinking).
__global__ __launch_bounds__(256) void attn_kernel(
    const float* __restrict__ query, const int* __restrict__ mask,
    const float* __restrict__ Kp, const float* __restrict__ Vp,
    const float* __restrict__ Wq, const float* __restrict__ bq,
    const float* __restrict__ Wo, const float* __restrict__ bo,
    float* __restrict__ out) {
  __shared__ float sWq[EMB][EMB];
  __shared__ float sWo[EMB][EMB];
  __shared__ float sbq[EMB];
  __shared__ float sbo[EMB];
  __shared__ float sX[16][EMB];
  __shared__ float sCtx[16][EMB + 1];
  __shared__ float sPart[2][16][EMB];   // [khalf][row][4h+d] partial ac
  __shared__ float sL[2][16][HEADS];    // [khalf][row][h]    partial l

  int t = threadIdx.x;
  int n = blockIdx.x >> 7;        // 128 q-tiles (of 16 rows) per batch
  int qt = blockIdx.x & 127;
  int qrow0 = qt * 16;

  int w = t >> 6;                 // wave 0..3
  int octet = w >> 1;             // row-octet 0..1 (rows 8*octet..+7)
  int kh = w & 1;                 // key half (1024 keys each)
  int lane = t & 63;
  int h = lane & 7;               // head
  int ks = lane >> 3;             // key split 0..7
  int ks4 = 4 * ks;
  int rbl = 8 * octet;

  for (int i = t; i < EMB * EMB; i += 256) {
    sWq[i >> 5][i & 31] = Wq[i];
    sWo[i >> 5][i & 31] = Wo[i];
  }
  if (t < EMB) { sbq[t] = bq[t]; sbo[t] = bo[t]; }
#pragma unroll
  for (int rr = 0; rr < 2; ++rr) {
    int r = (t >> 5) + 8 * rr, c = t & 31;
    sX[r][c] = query[((size_t)n * SEQ + qrow0 + r) * EMB + c];
  }
  __syncthreads();

  // q projection: this thread's 8 rows x head h's 4 dims,
  // scaled by (1/sqrt(32))*log2(e).
  const float SC = 0.17677669529663687f * 1.4426950408889634f;
  float q[8][4];
#pragma unroll
  for (int r = 0; r < 8; ++r)
#pragma unroll
    for (int d = 0; d < 4; ++d) q[r][d] = sbq[4 * h + d];
#pragma unroll
  for (int j = 0; j < EMB; ++j) {
    float w0 = sWq[j][4 * h + 0], w1 = sWq[j][4 * h + 1];
    float w2 = sWq[j][4 * h + 2], w3 = sWq[j][4 * h + 3];
#pragma unroll
    for (int r = 0; r < 8; ++r) {
      float x = sX[rbl + r][j];
      q[r][0] = fmaf(x, w0, q[r][0]);
      q[r][1] = fmaf(x, w1, q[r][1]);
      q[r][2] = fmaf(x, w2, q[r][2]);
      q[r][3] = fmaf(x, w3, q[r][3]);
    }
  }
#pragma unroll
  for (int r = 0; r < 8; ++r)
#pragma unroll
    for (int d = 0; d < 4; ++d) q[r][d] *= SC;

  // mask prologue: AND this wave's raw slice (8 rows x 1024 keys = 32 KB).
  // Per row: 256 int4; lane takes int4 index 64*c + lane (contiguous per c).
  const int* msl = mask + ((size_t)n * SEQ + qrow0 + rbl) * SEQ + kh * 1024;
  uint andv = 0xFFFFFFFFu;
#pragma unroll
  for (int rr = 0; rr < 8; ++rr) {
    const int4* mrow = (const int4*)(msl + (size_t)rr * SEQ);
#pragma unroll
    for (int c = 0; c < 4; ++c) {
      int4 v = mrow[64 * c + lane];
      andv &= (uint)v.x & (uint)v.y & (uint)v.z & (uint)v.w;
    }
  }
  bool allones = __all(andv == 0xFFFFFFFFu);

  const float* kptr = Kp + (size_t)n * SEQ * EMB + (size_t)kh * 1024 * EMB
                         + (size_t)ks4 * EMB + 4 * h;
  const float* vptr = Vp + (size_t)n * SEQ * EMB + (size_t)kh * 1024 * EMB
                         + (size_t)ks4 * EMB + 4 * h;

  float l[8], ac[8][4];
#pragma unroll
  for (int r = 0; r < 8; ++r) {
    l[r] = 0.0f;
#pragma unroll
    for (int d = 0; d < 4; ++d) ac[r][d] = 0.0f;
  }

  if (allones) {
    // hot path: zero mask work; 32 tiles, register double-buffer
    float4 ka[4], va[4], kb[4], vb[4];
    load_tile(kptr, vptr, ka, va);
    for (int i = 0; i < 15; ++i) {
      load_tile(kptr, vptr, kb, vb);
      compute_tile(ka, va, q, l, ac);
      load_tile(kptr, vptr, ka, va);
      compute_tile(kb, vb, q, l, ac);
    }
    load_tile(kptr, vptr, kb, vb);
    compute_tile(ka, va, q, l, ac);
    compute_tile(kb, vb, q, l, ac);
  } else {
    // cold path: raw mask int4 per row per tile
    for (int tile = 0; tile < 32; ++tile) {
      float4 ka[4], va[4];
      load_tile(kptr, vptr, ka, va);
      int4 MQ[8];
#pragma unroll
      for (int rr = 0; rr < 8; ++rr)
        MQ[rr] = *(const int4*)(msl + (size_t)rr * SEQ + tile * 32 + ks4);
      compute_tile_masked(ka, va, MQ, q, l, ac);
    }
  }

  // merge the 8 k-split partials within the wave (butterfly over lane bits 3-5)
#pragma unroll
  for (int d = 8; d <= 32; d <<= 1) {
#pragma unroll
    for (int r = 0; r < 8; ++r) {
      l[r] += __shfl_xor(l[r], d);
#pragma unroll
      for (int e = 0; e < 4; ++e) ac[r][e] += __shfl_xor(ac[r][e], d);
    }
  }

  // stash this wave's half-range partials
  if (ks < 4) {
#pragma unroll
    for (int r = 0; r < 8; ++r) {
      float v = (ks == 0) ? ac[r][0] : (ks == 1) ? ac[r][1]
              : (ks == 2) ? ac[r][2] : ac[r][3];
      sPart[kh][rbl + r][4 * h + ks] = v;
    }
  } else if (ks == 4) {
#pragma unroll
    for (int r = 0; r < 8; ++r) sL[kh][rbl + r][h] = l[r];
  }
  __syncthreads();

  // combine halves + normalize: 16 rows x 32 cols, 2 per thread
#pragma unroll
  for (int rr = 0; rr < 2; ++rr) {
    int r = (t >> 5) + 8 * rr, c = t & 31, hh = (t & 31) >> 2;
    float num = sPart[0][r][c] + sPart[1][r][c];
    float den = sL[0][r][hh] + sL[1][r][hh];
    sCtx[r][c] = num * __builtin_amdgcn_rcpf(den);
  }
  __syncthreads();

  // output projection: out[row][e] = bo[e] + sum_j ctx[row][j] * Wo[j][e]
#pragma unroll
  for (int rr = 0; rr < 2; ++rr) {
    int r = (t >> 5) + 8 * rr, e = t & 31;
    float o = sbo[e];
#pragma unroll
    for (int j = 0; j < EMB; ++j) o = fmaf(sCtx[r][j], sWo[j][e], o);
    out[((size_t)n * SEQ + qrow0 + r) * EMB + e] = o;
  }
}

extern "C" void kernel_launch(void* const* d_in, const int* in_sizes, int n_in,
                              void* d_out, int out_size, void* d_ws, size_t ws_size,
                              hipStream_t stream) {
  const float* query = (const float*)d_in[0];
  const float* key   = (const float*)d_in[1];
  const float* value = (const float*)d_in[2];
  const int*   mask  = (const int*)d_in[3];
  const float* Wq = (const float*)d_in[4];
  const float* bq = (const float*)d_in[5];
  const float* Wk = (const float*)d_in[6];
  const float* bk = (const float*)d_in[7];
  const float* Wv = (const float*)d_in[8];
  const float* bv = (const float*)d_in[9];
  const float* Wo = (const float*)d_in[10];
  const float* bo = (const float*)d_in[11];
  float* out = (float*)d_out;

  float* Kp = (float*)d_ws;                       // 1 MB
  float* Vp = Kp + (size_t)NB * SEQ * EMB;        // 1 MB

  proj_kv_kernel<<<dim3(2 * NB * SEQ / 8), dim3(256), 0, stream>>>(
      key, value, Wk, bk, Wv, bv, Kp, Vp);
  attn_kernel<<<dim3(NB * (SEQ / 16)), dim3(256), 0, stream>>>(
      query, mask, Kp, Vp, Wq, bq, Wo, bo, out);
}

// Round 15
// 70.165 us; speedup vs baseline: 1.0213x; 1.0213x over previous
//
#include <hip/hip_runtime.h>

#define NB 4
#define SEQ 2048
#define EMB 32
#define HEADS 8
#define HD 4

typedef float v2f __attribute__((ext_vector_type(2)));
typedef unsigned int uint;

__device__ __forceinline__ v2f splat2(float x) { v2f r; r.x = x; r.y = x; return r; }
__device__ __forceinline__ v2f pkfma(v2f a, v2f b, v2f c) {
  return __builtin_elementwise_fma(a, b, c);
}

// async global->LDS, 16 B per lane. LDS dest is wave-uniform base + lane*16;
// global src is per-lane (src already includes lane offset).
__device__ __forceinline__ void gll16(const float* src, float* ldsDst) {
  __builtin_amdgcn_global_load_lds(
      (const __attribute__((address_space(1))) void*)src,
      (__attribute__((address_space(3))) void*)ldsDst, 16, 0, 0);
}

// Fused: mask bit-pack (blocks [0, 16384)) + K/V projections (blocks after).
// Proven r5 kernel: ~12.4 us, mask read at near-HBM rate.
__global__ __launch_bounds__(256) void pack_proj_kernel(
    const int* __restrict__ mask, uint* __restrict__ pmw,
    const float* __restrict__ key, const float* __restrict__ value,
    const float* __restrict__ Wk, const float* __restrict__ bk,
    const float* __restrict__ Wv, const float* __restrict__ bv,
    float* __restrict__ Kp, float* __restrict__ Vp) {
  const int packBlocks = NB * SEQ * SEQ / 4 / 256;   // 16384
  if (blockIdx.x < packBlocks) {
    int g = blockIdx.x * 256 + threadIdx.x;          // int4 index
    const int4 v = ((const int4*)mask)[g];
    uint nib = (uint)(v.x != 0) | ((uint)(v.y != 0) << 1) |
               ((uint)(v.z != 0) << 2) | ((uint)(v.w != 0) << 3);
    int lane = threadIdx.x & 63;
    uint w = nib << (4 * (lane & 7));
    w |= __shfl_xor(w, 1);
    w |= __shfl_xor(w, 2);
    w |= __shfl_xor(w, 4);
    if ((lane & 7) == 0) pmw[g >> 3] = w;
  } else {
    const int half = NB * SEQ / 8;                   // 1024
    int blk2 = blockIdx.x - packBlocks;
    bool isV = blk2 >= half;
    const float* X = isV ? value : key;
    const float* W = isV ? Wv : Wk;
    const float* b = isV ? bv : bk;
    float* P = isV ? Vp : Kp;
    int blk = isV ? (blk2 - half) : blk2;

    __shared__ float sW[EMB][EMB];
    __shared__ float sb[EMB];
    __shared__ float sX[8][EMB];
    int t = threadIdx.x;
    for (int i = t; i < EMB * EMB; i += 256) sW[i >> 5][i & 31] = W[i];
    if (t < EMB) sb[t] = b[t];
    size_t row0 = (size_t)blk * 8;
    int r = t >> 5, c = t & 31;
    sX[r][c] = X[(row0 + r) * EMB + c];
    __syncthreads();
    float acc = sb[c];
#pragma unroll
    for (int d = 0; d < EMB; ++d) acc = fmaf(sX[r][d], sW[d][c], acc);
    P[(row0 + r) * EMB + c] = acc;
  }
}

// r13-proven v2f tile math (no-max softmax): 32 keys x 8 rows per wave-pass.
__device__ __forceinline__ void compute_math(
    const float4 (&KK)[4], const float4 (&VV)[4],
    const v2f (&q2)[4][4], v2f (&l2)[4], v2f (&ac2)[4][4]) {
#pragma unroll
  for (int p = 0; p < 4; ++p) {
    v2f pf[4];
#pragma unroll
    for (int j = 0; j < 4; ++j) {
      const float4 kk = KK[j];
      v2f s = pkfma(q2[p][0], splat2(kk.x),
              pkfma(q2[p][1], splat2(kk.y),
              pkfma(q2[p][2], splat2(kk.z), q2[p][3] * splat2(kk.w))));
      pf[j].x = __builtin_amdgcn_exp2f(s.x);
      pf[j].y = __builtin_amdgcn_exp2f(s.y);
    }
    l2[p] += (pf[0] + pf[1]) + (pf[2] + pf[3]);
#pragma unroll
    for (int j = 0; j < 4; ++j) {
      const float4 vv = VV[j];
      ac2[p][0] = pkfma(pf[j], splat2(vv.x), ac2[p][0]);
      ac2[p][1] = pkfma(pf[j], splat2(vv.y), ac2[p][1]);
      ac2[p][2] = pkfma(pf[j], splat2(vv.z), ac2[p][2]);
      ac2[p][3] = pkfma(pf[j], splat2(vv.w), ac2[p][3]);
    }
  }
}

// Masked cold-path math (packed words; correctness only, not taken in bench).
__device__ __forceinline__ void compute_math_masked(
    const float4 (&KK)[4], const float4 (&VV)[4],
    const uint (&MW)[8], int ks4,
    const v2f (&q2)[4][4], v2f (&l2)[4], v2f (&ac2)[4][4]) {
#pragma unroll
  for (int p = 0; p < 4; ++p) {
    v2f pf[4];
#pragma unroll
    for (int j = 0; j < 4; ++j) {
      const float4 kk = KK[j];
      v2f s = pkfma(q2[p][0], splat2(kk.x),
              pkfma(q2[p][1], splat2(kk.y),
              pkfma(q2[p][2], splat2(kk.z), q2[p][3] * splat2(kk.w))));
      pf[j].x = ((MW[2 * p + 0] >> (ks4 + j)) & 1u) ? __builtin_amdgcn_exp2f(s.x) : 0.0f;
      pf[j].y = ((MW[2 * p + 1] >> (ks4 + j)) & 1u) ? __builtin_amdgcn_exp2f(s.y) : 0.0f;
    }
    l2[p] += (pf[0] + pf[1]) + (pf[2] + pf[3]);
#pragma unroll
    for (int j = 0; j < 4; ++j) {
      const float4 vv = VV[j];
      ac2[p][0] = pkfma(pf[j], splat2(vv.x), ac2[p][0]);
      ac2[p][1] = pkfma(pf[j], splat2(vv.y), ac2[p][1]);
      ac2[p][2] = pkfma(pf[j], splat2(vv.z), ac2[p][2]);
      ac2[p][3] = pkfma(pf[j], splat2(vv.w), ac2[p][3]);
    }
  }
}

// Cold-path global tile load (r13-proven addressing).
__device__ __forceinline__ void load_tile_g(
    const float*& kptr, const float*& vptr,
    float4 (&KK)[4], float4 (&VV)[4]) {
  KK[0] = *(const float4*)(kptr);
  KK[1] = *(const float4*)(kptr + EMB);
  KK[2] = *(const float4*)(kptr + 2 * EMB);
  KK[3] = *(const float4*)(kptr + 3 * EMB);
  VV[0] = *(const float4*)(vptr);
  VV[1] = *(const float4*)(vptr + EMB);
  VV[2] = *(const float4*)(vptr + 2 * EMB);
  VV[3] = *(const float4*)(vptr + 3 * EMB);
  kptr += 32 * EMB; vptr += 32 * EMB;
}

// Fused q-projection + LDS-staged flash attention (no-max) + out projection.
// Block = 256 = 4 waves = 2 row-octets x 2 key-halves; 16 rows/block.
// K/V staged ONCE per block per 64-key tile into LDS (async global_load_lds,
// 3 buffers, staged 2 tiles ahead), shared by all 4 waves -> halves global
// K/V traffic vs r11 and decouples load latency from VGPR budget.
// Raw s_barrier + counted s_waitcnt vmcnt(4): staged loads stay in flight
// across barriers (a __syncthreads vmcnt(0) drain would serialize).
// Grid = NB*SEQ/16 = 512.
__global__ __launch_bounds__(256) void attn_kernel(
    const float* __restrict__ query, const uint* __restrict__ pmw,
    const float* __restrict__ Kp, const float* __restrict__ Vp,
    const float* __restrict__ Wq, const float* __restrict__ bq,
    const float* __restrict__ Wo, const float* __restrict__ bo,
    float* __restrict__ out) {
  __shared__ float sK[3][64][EMB];     // 24 KB
  __shared__ float sV[3][64][EMB];     // 24 KB
  __shared__ float sWq[EMB][EMB];
  __shared__ float sWo[EMB][EMB];
  __shared__ float sbq[EMB];
  __shared__ float sbo[EMB];
  __shared__ float sX[16][EMB];
  __shared__ float sCtx[16][EMB + 1];
  __shared__ float sPart[2][16][EMB];  // [kh][row][4h+d] partial ac
  __shared__ float sL[2][16][HEADS];   // [kh][row][h]    partial l
  __shared__ int sFlag[4];

  int t = threadIdx.x;
  int n = blockIdx.x >> 7;        // 128 q-tiles (of 16 rows) per batch
  int qt = blockIdx.x & 127;
  int qrow0 = qt * 16;

  int w = t >> 6;                 // wave 0..3
  int oc = w >> 1;                // row-octet 0..1 (rows 8*oc..+7)
  int kh = w & 1;                 // key half within each 64-key tile
  int lane = t & 63;
  int h = lane & 7;               // head
  int ks = lane >> 3;             // key split 0..7
  int ks4 = 4 * ks;
  int h4 = 4 * h;
  int rbl = 8 * oc;

  const float* Kg = Kp + (size_t)n * SEQ * EMB;
  const float* Vg = Vp + (size_t)n * SEQ * EMB;

  // ---- stage tiles 0 and 1 (async; drained by the weight __syncthreads) ----
#pragma unroll
  for (int tt = 0; tt < 2; ++tt) {
#pragma unroll
    for (int c = 0; c < 4; ++c) {
      int idx = w * 4 + c;                            // 0..15 chunks of 1 KB
      if (idx < 8) {
        gll16(Kg + (size_t)tt * 64 * EMB + idx * 256 + lane * 4,
              &sK[tt][0][0] + idx * 256);
      } else {
        gll16(Vg + (size_t)tt * 64 * EMB + (idx - 8) * 256 + lane * 4,
              &sV[tt][0][0] + (idx - 8) * 256);
      }
    }
  }

  // ---- weights / query / mask-allones prologue ----
  for (int i = t; i < EMB * EMB; i += 256) {
    sWq[i >> 5][i & 31] = Wq[i];
    sWo[i >> 5][i & 31] = Wo[i];
  }
  if (t < EMB) { sbq[t] = bq[t]; sbo[t] = bo[t]; }
#pragma unroll
  for (int rr = 0; rr < 2; ++rr) {
    int r = (t >> 5) + 8 * rr, c = t & 31;
    sX[r][c] = query[((size_t)n * SEQ + qrow0 + r) * EMB + c];
  }
  {
    // AND the block's 1024 packed mask words (16 rows x 64): 4 per thread
    const uint* mb = pmw + ((size_t)n * SEQ + qrow0 + (t >> 4)) * (SEQ / 32);
    uint4 mw = *(const uint4*)(mb + (t & 15) * 4);
    uint a = mw.x & mw.y & mw.z & mw.w;
    bool wall = __all(a == 0xFFFFFFFFu);
    if (lane == 0) sFlag[w] = wall ? 1 : 0;
  }
  __syncthreads();   // weights+flags ready; also drains staged tiles 0,1
  bool allones = sFlag[0] && sFlag[1] && sFlag[2] && sFlag[3];

  // q projection: this thread's 8 rows x head h's 4 dims, as 4 row-pair v2f,
  // scaled by (1/sqrt(32))*log2(e).
  const float SC = 0.17677669529663687f * 1.4426950408889634f;
  v2f q2[4][4];
#pragma unroll
  for (int p = 0; p < 4; ++p)
#pragma unroll
    for (int d = 0; d < 4; ++d) q2[p][d] = splat2(sbq[h4 + d]);
#pragma unroll
  for (int j = 0; j < EMB; ++j) {
    v2f w0 = splat2(sWq[j][h4 + 0]);
    v2f w1 = splat2(sWq[j][h4 + 1]);
    v2f w2 = splat2(sWq[j][h4 + 2]);
    v2f w3 = splat2(sWq[j][h4 + 3]);
#pragma unroll
    for (int p = 0; p < 4; ++p) {
      v2f x;
      x.x = sX[rbl + 2 * p + 0][j];
      x.y = sX[rbl + 2 * p + 1][j];
      q2[p][0] = pkfma(x, w0, q2[p][0]);
      q2[p][1] = pkfma(x, w1, q2[p][1]);
      q2[p][2] = pkfma(x, w2, q2[p][2]);
      q2[p][3] = pkfma(x, w3, q2[p][3]);
    }
  }
#pragma unroll
  for (int p = 0; p < 4; ++p)
#pragma unroll
    for (int d = 0; d < 4; ++d) q2[p][d] *= splat2(SC);

  v2f l2[4], ac2[4][4];
#pragma unroll
  for (int p = 0; p < 4; ++p) {
    l2[p] = splat2(0.0f);
#pragma unroll
    for (int d = 0; d < 4; ++d) ac2[p][d] = splat2(0.0f);
  }

  if (allones) {
    // ---- hot loop: 32 tiles of 64 keys; wave computes its kh 32-key half ----
    for (int tile = 0; tile < 32; ++tile) {
      int b = tile % 3;
      if (tile + 2 < 32) {
        int b2 = (tile + 2) % 3;
#pragma unroll
        for (int c = 0; c < 4; ++c) {
          int idx = w * 4 + c;
          if (idx < 8) {
            gll16(Kg + (size_t)(tile + 2) * 64 * EMB + idx * 256 + lane * 4,
                  &sK[b2][0][0] + idx * 256);
          } else {
            gll16(Vg + (size_t)(tile + 2) * 64 * EMB + (idx - 8) * 256 + lane * 4,
                  &sV[b2][0][0] + (idx - 8) * 256);
          }
        }
      }
      {
        int kb = kh * 32 + ks4;
        float4 KK[4], VV[4];
#pragma unroll
        for (int j = 0; j < 4; ++j) {
          KK[j] = *(const float4*)(&sK[b][kb + j][h4]);
          VV[j] = *(const float4*)(&sV[b][kb + j][h4]);
        }
        compute_math(KK, VV, q2, l2, ac2);
      }
      // own stages for tile+1 must land before anyone reads them next iter;
      // leave the 4 just-issued (tile+2) loads in flight.
      if (tile + 2 < 32) {
        asm volatile("s_waitcnt vmcnt(4)" ::: "memory");
      } else {
        asm volatile("s_waitcnt vmcnt(0)" ::: "memory");
      }
      __builtin_amdgcn_s_barrier();
    }
  } else {
    // ---- cold path: global loads + packed-word masking (r13-proven) ----
    const float* kptr = Kg + (size_t)kh * 1024 * EMB + (size_t)ks4 * EMB + h4;
    const float* vptr = Vg + (size_t)kh * 1024 * EMB + (size_t)ks4 * EMB + h4;
    const uint* mbase = pmw + ((size_t)n * SEQ + qrow0 + rbl) * (SEQ / 32) + kh * 32;
    for (int tile = 0; tile < 32; ++tile) {
      float4 KK[4], VV[4];
      load_tile_g(kptr, vptr, KK, VV);
      uint MW[8];
#pragma unroll
      for (int rr = 0; rr < 8; ++rr) MW[rr] = mbase[(size_t)rr * 64 + tile];
      compute_math_masked(KK, VV, MW, ks4, q2, l2, ac2);
    }
  }

  // merge the 8 k-split partials within the wave (butterfly over lane bits 3-5)
#pragma unroll
  for (int d = 8; d <= 32; d <<= 1) {
#pragma unroll
    for (int p = 0; p < 4; ++p) {
      l2[p].x += __shfl_xor(l2[p].x, d);
      l2[p].y += __shfl_xor(l2[p].y, d);
#pragma unroll
      for (int e = 0; e < 4; ++e) {
        ac2[p][e].x += __shfl_xor(ac2[p][e].x, d);
        ac2[p][e].y += __shfl_xor(ac2[p][e].y, d);
      }
    }
  }

  // stash this wave's half-range partials
#pragma unroll
  for (int p = 0; p < 4; ++p) {
    int r0 = rbl + 2 * p;
    if (ks < 4) {
      float vA = (ks == 0) ? ac2[p][0].x : (ks == 1) ? ac2[p][1].x
               : (ks == 2) ? ac2[p][2].x : ac2[p][3].x;
      float vB = (ks == 0) ? ac2[p][0].y : (ks == 1) ? ac2[p][1].y
               : (ks == 2) ? ac2[p][2].y : ac2[p][3].y;
      sPart[kh][r0 + 0][h4 + ks] = vA;
      sPart[kh][r0 + 1][h4 + ks] = vB;
    } else if (ks == 4) {
      sL[kh][r0 + 0][h] = l2[p].x;
      sL[kh][r0 + 1][h] = l2[p].y;
    }
  }
  __syncthreads();

  // combine halves + normalize: 16 rows x 32 cols, 2 per thread
#pragma unroll
  for (int rr = 0; rr < 2; ++rr) {
    int r = (t >> 5) + 8 * rr, c = t & 31, hh = (t & 31) >> 2;
    float num = sPart[0][r][c] + sPart[1][r][c];
    float den = sL[0][r][hh] + sL[1][r][hh];
    sCtx[r][c] = num * __builtin_amdgcn_rcpf(den);
  }
  __syncthreads();

  // output projection: out[row][e] = bo[e] + sum_j ctx[row][j] * Wo[j][e]
#pragma unroll
  for (int rr = 0; rr < 2; ++rr) {
    int r = (t >> 5) + 8 * rr, e = t & 31;
    float o = sbo[e];
#pragma unroll
    for (int j = 0; j < EMB; ++j) o = fmaf(sCtx[r][j], sWo[j][e], o);
    out[((size_t)n * SEQ + qrow0 + r) * EMB + e] = o;
  }
}

extern "C" void kernel_launch(void* const* d_in, const int* in_sizes, int n_in,
                              void* d_out, int out_size, void* d_ws, size_t ws_size,
                              hipStream_t stream) {
  const float* query = (const float*)d_in[0];
  const float* key   = (const float*)d_in[1];
  const float* value = (const float*)d_in[2];
  const int*   mask  = (const int*)d_in[3];
  const float* Wq = (const float*)d_in[4];
  const float* bq = (const float*)d_in[5];
  const float* Wk = (const float*)d_in[6];
  const float* bk = (const float*)d_in[7];
  const float* Wv = (const float*)d_in[8];
  const float* bv = (const float*)d_in[9];
  const float* Wo = (const float*)d_in[10];
  const float* bo = (const float*)d_in[11];
  float* out = (float*)d_out;

  float* Kp = (float*)d_ws;                          // 1 MB
  float* Vp = Kp + (size_t)NB * SEQ * EMB;           // 1 MB
  uint* pmw = (uint*)(Vp + (size_t)NB * SEQ * EMB);  // 2 MB packed mask bits

  const int packBlocks = NB * SEQ * SEQ / 4 / 256;   // 16384
  const int projBlocks = 2 * NB * SEQ / 8;           // 2048
  pack_proj_kernel<<<dim3(packBlocks + projBlocks), dim3(256), 0, stream>>>(
      mask, pmw, key, value, Wk, bk, Wv, bv, Kp, Vp);
  attn_kernel<<<dim3(NB * (SEQ / 16)), dim3(256), 0, stream>>>(
      query, pmw, Kp, Vp, Wq, bq, Wo, bo, out);
}